// Round 12
// baseline (213.606 us; speedup 1.0000x reference)
//
#include <hip/hip_runtime.h>
#include <math.h>

// B=4, S=4096, D=2048, E=64, K=2
#define NTOK    16384
#define DDIM    2048
#define NEXP    64
#define PSTRIDE (NTOK * NEXP)

#define AS1 __attribute__((address_space(1)))
#define AS3 __attribute__((address_space(3)))

typedef _Float16 half8   __attribute__((ext_vector_type(8)));
typedef float    floatx4 __attribute__((ext_vector_type(4)));

// ---------------------------------------------------------------------------
// W (fp32 [64][2048]) -> d_ws: 4 K-split regions of 128 KB, in the exact
// linear order the GEMM DMAs into LDS. Region ks, 16B chunk
// L = s*512 + pl*256 + e*4 + q'   (s = 32-k step 0..15, pl = hi/lo plane,
// e = expert, q' = q ^ ((e>>1)&3) bank swizzle) holding plane pl of
// W[e][ks*512 + s*32 + q*8 .. +8), lo scaled by 2^11.
// ---------------------------------------------------------------------------
__global__ __launch_bounds__(256) void wconv_kernel(
    const float* __restrict__ W, _Float16* __restrict__ ws)
{
    const int g  = blockIdx.x * 256 + threadIdx.x;   // 0..32767 chunks
    const int ks = g >> 13;
    const int L  = g & 8191;
    const int s  = L >> 9;
    const int pl = (L >> 8) & 1;
    const int e  = (L >> 2) & 63;
    const int qp = L & 3;
    const int q  = qp ^ ((e >> 1) & 3);
    const int k  = ks * 512 + s * 32 + q * 8;

    const float* src = &W[(size_t)e * DDIM + k];
    floatx4 w0 = *(const floatx4*)src;
    floatx4 w1 = *(const floatx4*)(src + 4);

    half8 o;
#pragma unroll
    for (int i = 0; i < 4; ++i) {
        float f0 = w0[i], f1 = w1[i];
        _Float16 h0 = (_Float16)f0, h1 = (_Float16)f1;
        if (pl == 0) { o[i] = h0; o[4 + i] = h1; }
        else {
            o[i]     = (_Float16)((f0 - (float)h0) * 2048.0f);
            o[4 + i] = (_Float16)((f1 - (float)h1) * 2048.0f);
        }
    }
    *(half8*)(ws + (size_t)g * 8) = o;
}

// ---------------------------------------------------------------------------
// Partial GEMM, barrier-free K-loop. Grid 256 = 64 M-tiles x 4 K-splits;
// 512 threads = 8 waves, wave = 32 tokens (2 sub-tiles of 16). B (128 KB
// hi/lo fp16) is staged ONCE into LDS (16 DMA + 1 barrier), then 16 iters
// of 32 k with x prefetched 2 ahead (regs, rotation) and B-frags ds_read
// 1 ahead -- nothing drains vmcnt, the x stream stays deep in flight.
// Partials (planes combined) to d_ws.
// ---------------------------------------------------------------------------
__global__ __launch_bounds__(512, 2) void gemm_partial(
    const float* __restrict__ x,
    const _Float16* __restrict__ ws,
    float* __restrict__ part)
{
    __shared__ __align__(16) _Float16 blds[65536];   // 128 KB

    const int tid  = threadIdx.x;
    const int lane = tid & 63;
    const int wid  = tid >> 6;          // 0..7
    const int bm   = blockIdx.x >> 2;   // M-tile
    const int ks   = blockIdx.x & 3;    // K-split
    const int mrow = lane & 15;
    const int quad = lane >> 4;

    // ---- stage B once: 128 KB via global_load_lds w16 ----
    {
        const char* gs = (const char*)ws + (size_t)ks * 131072 + (size_t)tid * 16;
        char*       ld = (char*)blds + tid * 16;
#pragma unroll
        for (int i = 0; i < 16; ++i)
            __builtin_amdgcn_global_load_lds(
                (const AS1 unsigned int*)(const void*)(gs + i * 8192),
                (AS3 unsigned int*)(void*)(ld + i * 8192), 16, 0, 0);
    }

    const float* xbase = x + (size_t)(bm * 256 + wid * 32 + mrow) * DDIM + ks * 512 + quad * 8;

    int ebase[4];
#pragma unroll
    for (int j = 0; j < 4; ++j) {
        const int e = j * 16 + mrow;
        ebase[j] = e * 32 + ((quad ^ ((e >> 1) & 3)) << 3);
    }

    floatx4 acc_hh[2][4], acc_md[2][4];
#pragma unroll
    for (int m = 0; m < 2; ++m)
#pragma unroll
        for (int j = 0; j < 4; ++j) { acc_hh[m][j] = (floatx4)0.0f; acc_md[m][j] = (floatx4)0.0f; }

#define XL(S, D)                                                               \
    {                                                                          \
        _Pragma("unroll")                                                      \
        for (int m_ = 0; m_ < 2; ++m_) {                                       \
            (D)[m_ * 2]     = *(const floatx4*)(xbase + (size_t)m_ * 16 * DDIM + (S) * 32); \
            (D)[m_ * 2 + 1] = *(const floatx4*)(xbase + (size_t)m_ * 16 * DDIM + (S) * 32 + 4); \
        }                                                                      \
    }

    floatx4 x0[4], x1[4], x2[4];
    XL(0, x0);
    XL(1, x1);

    __syncthreads();   // the ONLY barrier: B slice resident from here on

    half8 cbh[4], cbl[4], nbh[4], nbl[4];
#pragma unroll
    for (int j = 0; j < 4; ++j) {
        cbh[j] = *(const half8*)(blds + ebase[j]);
        cbl[j] = *(const half8*)(blds + 2048 + ebase[j]);
    }

#pragma unroll 2
    for (int s = 0; s < 16; ++s) {
        // issue next loads first: x(s+2) on vmcnt, B(s+1) on lgkm
        if (s + 2 < 16) XL(s + 2, x2);
        if (s + 1 < 16) {
            const _Float16* bp = blds + (s + 1) * 4096;
#pragma unroll
            for (int j = 0; j < 4; ++j) {
                nbh[j] = *(const half8*)(bp + ebase[j]);
                nbl[j] = *(const half8*)(bp + 2048 + ebase[j]);
            }
        }

#pragma unroll
        for (int m = 0; m < 2; ++m) {
            half8 a_hi, a_lo;
            floatx4 v0 = x0[m * 2], v1 = x0[m * 2 + 1];
#pragma unroll
            for (int q = 0; q < 4; ++q) {
                float fv = v0[q];
                _Float16 hh = (_Float16)fv;
                a_hi[q] = hh;
                a_lo[q] = (_Float16)((fv - (float)hh) * 2048.0f);
            }
#pragma unroll
            for (int q = 0; q < 4; ++q) {
                float fv = v1[q];
                _Float16 hh = (_Float16)fv;
                a_hi[4 + q] = hh;
                a_lo[4 + q] = (_Float16)((fv - (float)hh) * 2048.0f);
            }
#pragma unroll
            for (int j = 0; j < 4; ++j) {
                acc_hh[m][j] = __builtin_amdgcn_mfma_f32_16x16x32_f16(a_hi, cbh[j], acc_hh[m][j], 0, 0, 0);
                acc_md[m][j] = __builtin_amdgcn_mfma_f32_16x16x32_f16(a_hi, cbl[j], acc_md[m][j], 0, 0, 0);
                acc_md[m][j] = __builtin_amdgcn_mfma_f32_16x16x32_f16(a_lo, cbh[j], acc_md[m][j], 0, 0, 0);
            }
        }

        // rotate
#pragma unroll
        for (int i = 0; i < 4; ++i) { x0[i] = x1[i]; x1[i] = x2[i]; }
#pragma unroll
        for (int j = 0; j < 4; ++j) { cbh[j] = nbh[j]; cbl[j] = nbl[j]; }
    }

    // ---- write partials (planes combined), coalesced 256B stores ----
    float* pw = part + ((size_t)(ks * 64 + bm)) * 16384 + wid * 2048 + lane;
#pragma unroll
    for (int m = 0; m < 2; ++m)
#pragma unroll
        for (int j = 0; j < 4; ++j)
#pragma unroll
            for (int r = 0; r < 4; ++r)
                pw[m * 1024 + (j * 4 + r) * 64] =
                    acc_hh[m][j][r] + acc_md[m][j][r] * (1.0f / 2048.0f);
}

// ---------------------------------------------------------------------------
// Reduce 4 K-split partials per token, then softmax + stable top-2.
// Wave u owns 16 tokens: bm = u>>4, w8 = (u>>1)&7, m = u&1. (R10-validated.)
// ---------------------------------------------------------------------------
__global__ __launch_bounds__(256) void reduce_epilogue(
    const float* __restrict__ part,
    const float* __restrict__ bias,
    float* __restrict__ out)
{
    const int tid  = threadIdx.x;
    const int lane = tid & 63;
    const int u    = blockIdx.x * 4 + (tid >> 6);   // 0..1023
    const int bm   = u >> 4;
    const int w8   = (u >> 1) & 7;
    const int m    = u & 1;
    const int mrow = lane & 15;
    const int quad = lane >> 4;
    const int tb   = bm * 256 + w8 * 32 + m * 16;

    const float* pb = part + (size_t)bm * 16384 + w8 * 2048 + m * 1024 + lane;

    float lg[4][4];
#pragma unroll
    for (int j = 0; j < 4; ++j) {
        const float bj = bias[j * 16 + mrow];
#pragma unroll
        for (int r = 0; r < 4; ++r) {
            const int f = j * 4 + r;
            float s0 = pb[(size_t)0 * 1048576 + f * 64];
            float s1 = pb[(size_t)1 * 1048576 + f * 64];
            float s2 = pb[(size_t)2 * 1048576 + f * 64];
            float s3 = pb[(size_t)3 * 1048576 + f * 64];
            lg[j][r] = (s0 + s1) + (s2 + s3) + bj;
        }
    }

    const int c = mrow;
#pragma unroll
    for (int r = 0; r < 4; ++r) {
        const int trow = tb + quad * 4 + r;

        float mx = lg[0][r];
#pragma unroll
        for (int j = 1; j < 4; ++j) mx = fmaxf(mx, lg[j][r]);
#pragma unroll
        for (int off = 1; off <= 8; off <<= 1) mx = fmaxf(mx, __shfl_xor(mx, off));

        float pj[4], s = 0.0f;
#pragma unroll
        for (int j = 0; j < 4; ++j) { pj[j] = __expf(lg[j][r] - mx); s += pj[j]; }
#pragma unroll
        for (int off = 1; off <= 8; off <<= 1) s += __shfl_xor(s, off);
        const float rinv = 1.0f / s;

        // stable top-2 on logits (tie -> lower expert index)
        float v1 = -1e30f, v2 = -1e30f; int i1 = -1, i2 = -1;
#pragma unroll
        for (int j = 0; j < 4; ++j) {
            float v = lg[j][r]; int e = j * 16 + c;
            if (v > v1 || (v == v1 && e < i1)) { v2 = v1; i2 = i1; v1 = v; i1 = e; }
            else if (v > v2 || (v == v2 && e < i2)) { v2 = v; i2 = e; }
        }
#pragma unroll
        for (int off = 1; off <= 8; off <<= 1) {
            float u1 = __shfl_xor(v1, off); int q1 = __shfl_xor(i1, off);
            float u2 = __shfl_xor(v2, off); int q2 = __shfl_xor(i2, off);
            if (u1 > v1 || (u1 == v1 && q1 < i1)) {
                if (v1 > u2 || (v1 == u2 && i1 < q2)) { v2 = v1; i2 = i1; }
                else                                   { v2 = u2; i2 = q2; }
                v1 = u1; i1 = q1;
            } else {
                if (u1 > v2 || (u1 == v2 && q1 < i2)) { v2 = u1; i2 = q1; }
            }
        }

#pragma unroll
        for (int j = 0; j < 4; ++j) {
            const int col = j * 16 + c;
            const size_t o = (size_t)trow * NEXP + col;
            out[o]           = (col == i1 || col == i2) ? 1.0f : 0.0f;
            out[PSTRIDE + o] = pj[j] * rinv;
        }
    }
}

extern "C" void kernel_launch(void* const* d_in, const int* in_sizes, int n_in,
                              void* d_out, int out_size, void* d_ws, size_t ws_size,
                              hipStream_t stream) {
    const float* x = (const float*)d_in[0];   // [4,4096,2048] f32
    const float* W = (const float*)d_in[1];   // [64,2048] f32
    const float* b = (const float*)d_in[2];   // [64] f32
    (void)in_sizes; (void)n_in; (void)out_size; (void)ws_size;
    float* out = (float*)d_out;               // [masks | probs]

    _Float16* ws  = (_Float16*)d_ws;                     // 512 KB W hi/lo
    float*    prt = (float*)((char*)d_ws + (1 << 19));   // 16 MB partials

    hipLaunchKernelGGL(wconv_kernel,    dim3(128), dim3(256), 0, stream, W, ws);
    hipLaunchKernelGGL(gemm_partial,    dim3(256), dim3(512), 0, stream, x, ws, prt);
    hipLaunchKernelGGL(reduce_epilogue, dim3(256), dim3(256), 0, stream, prt, b, out);
}